// Round 17
// baseline (705.767 us; speedup 1.0000x reference)
//
#include <hip/hip_runtime.h>

// UniversalSAE: z = TopK32((x - pre_bias) @ enc_w.T), rec_i = z @ dec_w_i.T + post_bias_i
// R17: R16 with RESCORE_TOP reverted 36->40 (slack-8 on every row; slack-4
// everywhere failed R16 — bf16-key rank noise flips ~1e-4/row at slack 4).
// Keeps R16's two safe changes: NT score stores + merged prep kernel.

#define BATCH  16384
#define HIDDEN 8192
#define DIM0   512
#define DIM1   768
#define TOPK   32
#define CAND_MAX 256
#define LIST_CAP 128
#define RESCORE_TOP 40
#define STAGE_CAP 32
#define CNT_STRIDE 16     // one 64B cache line per row counter
#define WIN_LO 36
#define WIN_HI 64

// probe seeds for the fallback bisect
#define KLO_G 0xBECDu
#define KHI_G 0xC020u

typedef __attribute__((ext_vector_type(8))) short bf16x8;
typedef __attribute__((ext_vector_type(8))) unsigned short u16x8;
typedef __attribute__((ext_vector_type(4))) float f32x4;

__device__ __forceinline__ unsigned fkey16(unsigned short h) {
    return (h & 0x8000u) ? (unsigned)((~h) & 0xFFFFu) : (unsigned)(h | 0x8000u);
}
__device__ __forceinline__ unsigned short f2b(float f) {  // fp32 -> bf16 RNE
    unsigned u = __float_as_uint(f);
    unsigned r = (u + 0x7FFFu + ((u >> 16) & 1u)) >> 16;
    return (unsigned short)r;
}
__device__ __forceinline__ float b2f(unsigned short h) {
    return __uint_as_float(((unsigned)h) << 16);
}
__device__ __forceinline__ void load_lds16(const void* g, void* l) {
    __builtin_amdgcn_global_load_lds((const __attribute__((address_space(1))) void*)g,
                                     (__attribute__((address_space(3))) void*)l, 16, 0, 0);
}
__device__ __forceinline__ unsigned fkey32(float f) {
    unsigned u = __float_as_uint(f);
    return (u & 0x80000000u) ? ~u : (u | 0x80000000u);
}

// ===========================================================================
__global__ void zero_cnt(int* __restrict__ cnt)
{
    cnt[blockIdx.x * 256 + threadIdx.x] = 0;   // grid covers BATCH*CNT_STRIDE
}

// ===========================================================================
// merged prep: blocks [0,4096) convert x-pb & enc_w to bf16 (grid-stride);
// blocks [4096,8192) transpose dec0 tiles; blocks [8192,14336) dec1 tiles.
// ===========================================================================
template<int SRC>
__device__ __forceinline__ void convert_impl(
    const float* __restrict__ x, const float* __restrict__ pb,
    const float* __restrict__ w,
    unsigned short* __restrict__ xb, unsigned short* __restrict__ wb)
{
    constexpr int D = SRC ? DIM1 : DIM0;
    const int nx4 = BATCH * D / 4;
    const int nw4 = HIDDEN * D / 4;
    for (int i = blockIdx.x * blockDim.x + threadIdx.x; i < nx4 + nw4;
         i += 4096 * 256) {
        if (i < nx4) {
            float4 v = ((const float4*)x)[i];
            const int k = (i * 4) % D;
            v.x -= pb[k]; v.y -= pb[k + 1]; v.z -= pb[k + 2]; v.w -= pb[k + 3];
            ushort4 o; o.x = f2b(v.x); o.y = f2b(v.y); o.z = f2b(v.z); o.w = f2b(v.w);
            ((ushort4*)xb)[i] = o;
        } else {
            const float4 v = ((const float4*)w)[i - nx4];
            ushort4 o; o.x = f2b(v.x); o.y = f2b(v.y); o.z = f2b(v.z); o.w = f2b(v.w);
            ((ushort4*)wb)[i - nx4] = o;
        }
    }
}

__device__ __forceinline__ void transpose_tile(
    const float* __restrict__ dec, unsigned short* __restrict__ decT,
    int DD, int hb, int db, float (*t)[33])
{
    const int tid = threadIdx.x;
    const int lx = tid & 31, ly = tid >> 5;    // (32,8)
#pragma unroll
    for (int s = 0; s < 32; s += 8)
        t[ly + s][lx] = dec[(size_t)(db + ly + s) * HIDDEN + hb + lx];
    __syncthreads();
#pragma unroll
    for (int s = 0; s < 32; s += 8)
        decT[(size_t)(hb + ly + s) * DD + db + lx] = f2b(t[lx][ly + s]);
}

__global__ void prep_all(const float* __restrict__ x0, const float* __restrict__ x1,
                         const float* __restrict__ pb0, const float* __restrict__ pb1,
                         const float* __restrict__ w0, const float* __restrict__ w1,
                         const float* __restrict__ dw0, const float* __restrict__ dw1,
                         const int* __restrict__ srcp,
                         unsigned short* __restrict__ xb, unsigned short* __restrict__ wb,
                         unsigned short* __restrict__ dTb0, unsigned short* __restrict__ dTb1)
{
    __shared__ float t[32][33];
    const int bid = blockIdx.x;
    if (bid < 4096) {
        if (*srcp == 0) convert_impl<0>(x0, pb0, w0, xb, wb);
        else            convert_impl<1>(x1, pb1, w1, xb, wb);
    } else if (bid < 8192) {
        const int ti = bid - 4096;                 // 256 x 16 tiles
        transpose_tile(dw0, dTb0, DIM0, (ti & 255) * 32, (ti >> 8) * 32, t);
    } else {
        const int ti = bid - 8192;                 // 256 x 24 tiles
        transpose_tile(dw1, dTb1, DIM1, (ti & 255) * 32, (ti >> 8) * 32, t);
    }
}

// ===========================================================================
// GEMM: bf16 scores (NT) into first 16KB of each fp32 z row; LDS-aggregated
// keyed screening -> per-row u32 lists; bx>=32 blocks NT-zero back half.
// ===========================================================================
template<int SRC>
__device__ __forceinline__ void gemm_impl(
    const unsigned short* __restrict__ xb, const unsigned short* __restrict__ wb,
    float* __restrict__ z, int* __restrict__ cnt, unsigned* __restrict__ clist,
    unsigned short* As, unsigned short* Bs)
{
    constexpr int D = SRC ? DIM1 : DIM0;
    constexpr unsigned KTH = SRC ? 0xBF86u : 0xBF5Du;  // ~48/8192 quantile

    const int nwg = gridDim.x;
    int id = blockIdx.x;
    id = (id & 7) * (nwg >> 3) + (id >> 3);      // XCD swizzle (nwg % 8 == 0)
    const int bx = id & 63;
    const int by = id >> 6;
    const int m0 = by * 128, n0 = bx * 128;

    const int tid  = threadIdx.x;
    const int lane = tid & 63;
    const int wid  = tid >> 6;
    const int wr   = wid >> 1;
    const int wc   = wid & 1;
    const int l15  = lane & 15;
    const int g    = lane >> 4;

    f32x4 acc[4][4];
#pragma unroll
    for (int i = 0; i < 4; ++i)
#pragma unroll
        for (int j = 0; j < 4; ++j) acc[i][j] = (f32x4){0.f, 0.f, 0.f, 0.f};

    for (int k0 = 0; k0 < D; k0 += 64) {
#pragma unroll
        for (int q = 0; q < 4; ++q) {
            const int c   = wid * 256 + q * 64 + lane;
            const int row = c >> 3, jb = c & 7;
            const int j   = jb ^ (row & 7);      // pre-swizzled source (rule #21)
            load_lds16(xb + (size_t)(m0 + row) * D + k0 + j * 8,
                       As + (size_t)(wid * 256 + q * 64) * 8);
            load_lds16(wb + (size_t)(n0 + row) * D + k0 + j * 8,
                       Bs + (size_t)(wid * 256 + q * 64) * 8);
        }
        __syncthreads();

#pragma unroll
        for (int kk = 0; kk < 2; ++kk) {
            bf16x8 a[4], b[4];
#pragma unroll
            for (int f = 0; f < 4; ++f) {
                const int rA = wr * 64 + f * 16 + l15;
                const int sA = ((kk * 4 + g) ^ (rA & 7)) * 16;
                a[f] = *(const bf16x8*)((const char*)As + rA * 128 + sA);
                const int rB = wc * 64 + f * 16 + l15;
                const int sB = ((kk * 4 + g) ^ (rB & 7)) * 16;
                b[f] = *(const bf16x8*)((const char*)Bs + rB * 128 + sB);
            }
#pragma unroll
            for (int fi = 0; fi < 4; ++fi)
#pragma unroll
                for (int fj = 0; fj < 4; ++fj)
                    acc[fi][fj] = __builtin_amdgcn_mfma_f32_16x16x32_bf16(
                        a[fi], b[fj], acc[fi][fj], 0, 0, 0);
        }
        __syncthreads();
    }
    // K-loop done; As/Bs free for epilogue aliasing (barrier above drained)

    unsigned* staging   = (unsigned*)As;         // 128*32 u32 = 16 KB
    int*      cnt_local = (int*)Bs;              // 128 ints
    int*      base_sh   = (int*)Bs + 128;        // 128 ints

    if (tid < 128) cnt_local[tid] = 0;
    __syncthreads();

    // epilogue: bf16 scores (NT) + LDS-local keyed candidate collection
#pragma unroll
    for (int fi = 0; fi < 4; ++fi) {
        const int rl0 = wr * 64 + fi * 16 + g * 4;        // local row base
#pragma unroll
        for (int fj = 0; fj < 4; ++fj) {
            const int col = n0 + wc * 64 + fj * 16 + l15;
#pragma unroll
            for (int r = 0; r < 4; ++r) {
                const unsigned short sb = f2b(acc[fi][fj][r]);
                unsigned short* zs =
                    (unsigned short*)((char*)z + (size_t)(m0 + rl0 + r) * (HIDDEN * 4));
                __builtin_nontemporal_store(sb, zs + col);
                const unsigned k16 = fkey16(sb);
                if (k16 > KTH) {
                    const int ls = atomicAdd(&cnt_local[rl0 + r], 1);
                    if (ls < STAGE_CAP)
                        staging[(rl0 + r) * STAGE_CAP + ls] =
                            (k16 << 16) | (unsigned)(8191 - col);
                }
            }
        }
    }
    __syncthreads();

    // one padded global atomic per (block,row) with n>0
    if (tid < 128) {
        const int n = cnt_local[tid];
        if (n > 0) {
            const int add = (n > STAGE_CAP) ? 1000 : n;   // overflow -> fallback path
            base_sh[tid] = atomicAdd(&cnt[(size_t)(m0 + tid) * CNT_STRIDE], add);
        }
    }
    __syncthreads();

    // flush staged candidates to global list
    if (tid < 128) {
        const int n = min(cnt_local[tid], STAGE_CAP);
        if (n > 0) {
            const int base = base_sh[tid];
            for (int j = 0; j < n; ++j) {
                const int pos = base + j;
                if (pos < LIST_CAP)
                    clist[(size_t)(m0 + tid) * LIST_CAP + pos] =
                        staging[tid * STAGE_CAP + j];
            }
        }
    }

    // back-half zero: fp32 cols [4096 + (bx-32)*128, +128) for rows [m0, m0+128)
    if (bx >= 32) {
        const f32x4 zv = (f32x4){0.f, 0.f, 0.f, 0.f};
        const int c4 = (4096 >> 2) + (bx - 32) * 32 + (tid & 31);
#pragma unroll
        for (int pass = 0; pass < 16; ++pass) {
            const int r = m0 + pass * 8 + (tid >> 5);
            __builtin_nontemporal_store(zv, (f32x4*)(z + (size_t)r * HIDDEN) + c4);
        }
    }
}

__global__ __launch_bounds__(256, 2)
void gemm_bf16(const unsigned short* __restrict__ xb, const unsigned short* __restrict__ wb,
               const int* __restrict__ srcp, float* __restrict__ z,
               int* __restrict__ cnt, unsigned* __restrict__ clist)
{
    __shared__ unsigned short As[128 * 64];
    __shared__ unsigned short Bs[128 * 64];
    if (*srcp == 0) gemm_impl<0>(xb, wb, z, cnt, clist, As, Bs);
    else            gemm_impl<1>(xb, wb, z, cnt, clist, As, Bs);
}

// ===========================================================================
// topk: list path (cnt in [36,128]) or full-screen fallback; both produce
// packed centry[]; rank by approx key -> rescore approx-top-40 exactly ->
// exact top-32 -> scatter + batched decode.
// ===========================================================================
template<int SRC>
__device__ __forceinline__ void topk_impl(
    float* __restrict__ z,
    const float* __restrict__ xsrc, const float* __restrict__ pb,
    const float* __restrict__ ew,
    const unsigned short* __restrict__ dTb0, const unsigned short* __restrict__ dTb1,
    const float* __restrict__ po0, const float* __restrict__ po1,
    float* __restrict__ rec0, float* __restrict__ rec1,
    const int* __restrict__ cnt, const unsigned* __restrict__ clist,
    float* xs, unsigned* centry, int* cidx, float* cval, unsigned char* cflag,
    int* counts, unsigned* pcounts, int* s_cnt, float* selv, int* seli)
{
    constexpr int D = SRC ? DIM1 : DIM0;

    const int tid = threadIdx.x;
    const size_t row = blockIdx.x;
    float* __restrict__ zrow = z + row * HIDDEN;
    const unsigned short* __restrict__ zsrow =
        (const unsigned short*)((const char*)z + row * (HIDDEN * 4));

    // stage exact (x - pb) row first (loads issue earliest)
    if (tid < D / 4) {
        const float4 xv = ((const float4*)(xsrc + row * D))[tid];
        const float4 pv = ((const float4*)pb)[tid];
        ((float4*)xs)[tid] = make_float4(xv.x - pv.x, xv.y - pv.y,
                                         xv.z - pv.z, xv.w - pv.w);
    }
    if (tid == 0) *s_cnt = 0;

    const int cn = cnt[row * CNT_STRIDE];
    const bool uselist = (cn >= WIN_LO && cn <= LIST_CAP);
    const f32x4 zv4 = (f32x4){0.f, 0.f, 0.f, 0.f};
    int cnC;

    if (uselist) {
        // keyed candidate list from GEMM; skip score read + bisect entirely
        if (tid < cn) centry[tid] = clist[row * LIST_CAP + tid];
#pragma unroll
        for (int s = 0; s < 4; ++s)
            __builtin_nontemporal_store(zv4, (f32x4*)&zrow[(size_t)(s * 256 + tid) * 4]);
        __syncthreads();
        cnC = cn;
    } else {
        // fallback: full screen (keys -> probe -> bisect -> collect packed)
        unsigned pkey[16];
#pragma unroll
        for (int s = 0; s < 4; ++s) {
            const u16x8 v = *(const u16x8*)(zsrow + (size_t)(s * 256 + tid) * 8);
#pragma unroll
            for (int p = 0; p < 4; ++p)
                pkey[s * 4 + p] = fkey16(v[2 * p]) | (fkey16(v[2 * p + 1]) << 16);
        }
#pragma unroll
        for (int s = 0; s < 4; ++s)
            __builtin_nontemporal_store(zv4, (f32x4*)&zrow[(size_t)(s * 256 + tid) * 4]);

        {
            int clo = 0, chi = 0;
#pragma unroll
            for (int p = 0; p < 16; ++p) {
                const unsigned klo16 = pkey[p] & 0xFFFFu, khi16 = pkey[p] >> 16;
                clo += (klo16 > KLO_G) ? 1 : 0;  chi += (klo16 > KHI_G) ? 1 : 0;
                clo += (khi16 > KLO_G) ? 1 : 0;  chi += (khi16 > KHI_G) ? 1 : 0;
            }
            unsigned pk = (unsigned)clo | ((unsigned)chi << 16);
#pragma unroll
            for (int off = 32; off; off >>= 1) pk += __shfl_xor(pk, off);
            if ((tid & 63) == 0) pcounts[tid >> 6] = pk;
        }
        __syncthreads();
        const unsigned ptot = pcounts[0] + pcounts[1] + pcounts[2] + pcounts[3];
        const int tot_lo = (int)(ptot & 0xFFFFu), tot_hi = (int)(ptot >> 16);

        unsigned kappa;
        int found = 0;
        if (tot_lo >= WIN_LO && tot_lo <= WIN_HI)      { kappa = KLO_G; found = 1; }
        else if (tot_hi >= WIN_LO && tot_hi <= WIN_HI) { kappa = KHI_G; found = 1; }
        if (!found) {
            unsigned lo = 0u, hi = 65535u;
            if (tot_lo > WIN_HI) lo = KLO_G;
            if (tot_lo < WIN_LO) hi = KLO_G;
            if (tot_hi > WIN_HI) lo = KHI_G;
            if (tot_hi < WIN_LO) hi = (hi < KHI_G) ? hi : KHI_G;
            kappa = lo;
            for (int it = 0; it < 18; ++it) {
                const unsigned mid = (lo + hi) >> 1;
                int c = 0;
#pragma unroll
                for (int p = 0; p < 16; ++p) {
                    c += ((pkey[p] & 0xFFFFu) > mid) ? 1 : 0;
                    c += ((pkey[p] >> 16)     > mid) ? 1 : 0;
                }
#pragma unroll
                for (int off = 32; off; off >>= 1) c += __shfl_xor(c, off);
                if ((tid & 63) == 0) counts[(it & 1) * 4 + (tid >> 6)] = c;
                __syncthreads();
                const int* cb = counts + (it & 1) * 4;
                const int tot = cb[0] + cb[1] + cb[2] + cb[3];
                if (tot >= WIN_LO && tot <= WIN_HI) { kappa = mid; break; }
                if (tot > WIN_HI) lo = mid; else hi = mid;
                kappa = lo;
                if (hi - lo <= 1u) break;
            }
        }

#pragma unroll
        for (int p = 0; p < 16; ++p) {
#pragma unroll
            for (int h = 0; h < 2; ++h) {
                const unsigned k16 = h ? (pkey[p] >> 16) : (pkey[p] & 0xFFFFu);
                if (k16 > kappa) {
                    const int j = 2 * p + h;
                    const int slot = atomicAdd(s_cnt, 1);
                    if (slot < CAND_MAX) {
                        const int idx = ((j >> 3) * 256 + tid) * 8 + (j & 7);
                        centry[slot] = (k16 << 16) | (unsigned)(8191 - idx);
                    }
                }
            }
        }
        __syncthreads();
        cnC = min(*s_cnt, CAND_MAX);
    }

    // rank by approx key (desc; ties -> lower col wins), keep approx-top-40.
    // Entries are distinct -> unique ranks -> no write conflicts.
    const int C = min(cnC, RESCORE_TOP);
    if (tid < cnC) {
        const unsigned e = centry[tid];
        int rank = 0;
        for (int j = 0; j < cnC; ++j) rank += (centry[j] > e) ? 1 : 0;
        if (rank < RESCORE_TOP) cidx[rank] = 8191 - (int)(e & 0xFFFFu);
    }
    __syncthreads();

    // exact fp32 rescore: 16-lane groups; whole candidate row in one burst
    {
        constexpr int NB = D / 64;                // float4s per lane (8 or 12)
        const int grp = tid >> 4, j16 = tid & 15; // 16 groups of 16 lanes
        for (int c = grp; c < C; c += 16) {
            const float* __restrict__ wrow = ew + (size_t)cidx[c] * D;
            float4 wv[NB];
#pragma unroll
            for (int u = 0; u < NB; ++u)
                wv[u] = *(const float4*)&wrow[(u * 16 + j16) * 4];
            float4 a4 = make_float4(0.f, 0.f, 0.f, 0.f);
#pragma unroll
            for (int u = 0; u < NB; ++u) {
                const float4 x4 = *(const float4*)&xs[(u * 16 + j16) * 4];
                a4.x = fmaf(x4.x, wv[u].x, a4.x);
                a4.y = fmaf(x4.y, wv[u].y, a4.y);
                a4.z = fmaf(x4.z, wv[u].z, a4.z);
                a4.w = fmaf(x4.w, wv[u].w, a4.w);
            }
            float a = (a4.x + a4.y) + (a4.z + a4.w);
            a += __shfl_xor(a, 1);
            a += __shfl_xor(a, 2);
            a += __shfl_xor(a, 4);
            a += __shfl_xor(a, 8);
            if (j16 == 0) cval[c] = a;
        }
    }
    __syncthreads();

    // exact top-32 among C candidates (val desc, idx asc) — order-independent
    if (tid < C) {
        const float v = cval[tid];
        const int  ix = cidx[tid];
        int rank = 0;
        for (int j = 0; j < C; ++j) {
            const float vj = cval[j];
            rank += (vj > v || (vj == v && cidx[j] < ix)) ? 1 : 0;
        }
        cflag[tid] = (rank < TOPK) ? 1 : 0;
    }
    __syncthreads();
    if (tid < C && cflag[tid]) {
        const int ix = cidx[tid];
        int sr = 0;
        for (int j = 0; j < C; ++j) sr += (cflag[j] && cidx[j] < ix) ? 1 : 0;
        selv[sr] = cval[tid];
        seli[sr] = ix;
    }
    __syncthreads();

    // scatter 32 exact values (front zero above, back half by GEMM)
    if (tid < TOPK) zrow[seli[tid]] = selv[tid];

    // batched sparse decode: thread -> 4 consecutive outputs; 16 rows in flight
#pragma unroll
    for (int pass = 0; pass < 2; ++pass) {
        const int slot = pass * 256 + tid;
        if (slot < (DIM0 + DIM1) / 4) {
            const bool is0 = slot < DIM0 / 4;
            const int d0 = is0 ? slot * 4 : (slot - DIM0 / 4) * 4;
            const int DD = is0 ? DIM0 : DIM1;
            const unsigned short* __restrict__ dT = is0 ? dTb0 : dTb1;
            const float* __restrict__ po = is0 ? po0 : po1;
            f32x4 a;
            {
                const float4 p4 = *(const float4*)&po[d0];
                a = (f32x4){p4.x, p4.y, p4.z, p4.w};
            }
#pragma unroll
            for (int b = 0; b < TOPK / 16; ++b) {
                ushort4 wv[16];
#pragma unroll
                for (int u = 0; u < 16; ++u)
                    wv[u] = *(const ushort4*)&dT[(size_t)seli[b * 16 + u] * DD + d0];
#pragma unroll
                for (int u = 0; u < 16; ++u) {
                    const float sv = selv[b * 16 + u];
                    a.x = fmaf(sv, b2f(wv[u].x), a.x);
                    a.y = fmaf(sv, b2f(wv[u].y), a.y);
                    a.z = fmaf(sv, b2f(wv[u].z), a.z);
                    a.w = fmaf(sv, b2f(wv[u].w), a.w);
                }
            }
            float* __restrict__ out = is0 ? (rec0 + row * DIM0 + d0)
                                          : (rec1 + row * DIM1 + d0);
            __builtin_nontemporal_store(a, (f32x4*)out);
        }
    }
}

__global__ __launch_bounds__(256, 4)
void topk_rescore_decode(float* __restrict__ z,
                         const float* __restrict__ x0, const float* __restrict__ x1,
                         const float* __restrict__ pb0, const float* __restrict__ pb1,
                         const float* __restrict__ ew0, const float* __restrict__ ew1,
                         const unsigned short* __restrict__ dTb0,
                         const unsigned short* __restrict__ dTb1,
                         const float* __restrict__ po0, const float* __restrict__ po1,
                         float* __restrict__ rec0, float* __restrict__ rec1,
                         const int* __restrict__ srcp,
                         const int* __restrict__ cnt, const unsigned* __restrict__ clist)
{
    __shared__ float         xs[DIM1];
    __shared__ unsigned      centry[CAND_MAX];
    __shared__ int           cidx[RESCORE_TOP];
    __shared__ float         cval[RESCORE_TOP];
    __shared__ unsigned char cflag[RESCORE_TOP];
    __shared__ int           counts[2 * 4];
    __shared__ unsigned      pcounts[4];
    __shared__ int           s_cnt;
    __shared__ float         selv[TOPK];
    __shared__ int           seli[TOPK];

    if (*srcp == 0)
        topk_impl<0>(z, x0, pb0, ew0, dTb0, dTb1, po0, po1, rec0, rec1, cnt, clist,
                     xs, centry, cidx, cval, cflag, counts, pcounts, &s_cnt, selv, seli);
    else
        topk_impl<1>(z, x1, pb1, ew1, dTb0, dTb1, po0, po1, rec0, rec1, cnt, clist,
                     xs, centry, cidx, cval, cflag, counts, pcounts, &s_cnt, selv, seli);
}

// ===========================================================================
// FALLBACK PATH (round-1, known-pass) — used only if ws is too small
// ===========================================================================

__global__ __launch_bounds__(256, 2)
void encode_gemm(const float* __restrict__ x0, const float* __restrict__ x1,
                 const float* __restrict__ pb0, const float* __restrict__ pb1,
                 const float* __restrict__ w0, const float* __restrict__ w1,
                 const int* __restrict__ srcp, float* __restrict__ z)
{
    const int src = *srcp;
    const float* __restrict__ x  = (src == 0) ? x0 : x1;
    const float* __restrict__ pb = (src == 0) ? pb0 : pb1;
    const float* __restrict__ w  = (src == 0) ? w0 : w1;
    const int D = (src == 0) ? DIM0 : DIM1;

    __shared__ float As[16][132];
    __shared__ float Bs[16][132];

    const int tid = threadIdx.x;
    const int m0 = blockIdx.y * 128;
    const int n0 = blockIdx.x * 128;

    const int cA0 = tid,          cA1 = tid + 256;
    const int r0  = cA0 >> 2,     kq0 = (cA0 & 3) * 4;
    const int r1  = cA1 >> 2,     kq1 = (cA1 & 3) * 4;

    const int mf = (tid & 15) * 4;
    const int nf = (tid >> 4) * 4;

    float acc[8][8];
#pragma unroll
    for (int i = 0; i < 8; ++i)
#pragma unroll
        for (int j = 0; j < 8; ++j) acc[i][j] = 0.0f;

    for (int k0 = 0; k0 < D; k0 += 16) {
        const float4 av0 = *(const float4*)(x + (size_t)(m0 + r0) * D + k0 + kq0);
        const float4 av1 = *(const float4*)(x + (size_t)(m0 + r1) * D + k0 + kq1);
        const float4 pv0 = *(const float4*)(pb + k0 + kq0);
        const float4 pv1 = *(const float4*)(pb + k0 + kq1);
        const float4 bv0 = *(const float4*)(w + (size_t)(n0 + r0) * D + k0 + kq0);
        const float4 bv1 = *(const float4*)(w + (size_t)(n0 + r1) * D + k0 + kq1);
        As[kq0 + 0][r0] = av0.x - pv0.x;
        As[kq0 + 1][r0] = av0.y - pv0.y;
        As[kq0 + 2][r0] = av0.z - pv0.z;
        As[kq0 + 3][r0] = av0.w - pv0.w;
        As[kq1 + 0][r1] = av1.x - pv1.x;
        As[kq1 + 1][r1] = av1.y - pv1.y;
        As[kq1 + 2][r1] = av1.z - pv1.z;
        As[kq1 + 3][r1] = av1.w - pv1.w;
        Bs[kq0 + 0][r0] = bv0.x;
        Bs[kq0 + 1][r0] = bv0.y;
        Bs[kq0 + 2][r0] = bv0.z;
        Bs[kq0 + 3][r0] = bv0.w;
        Bs[kq1 + 0][r1] = bv1.x;
        Bs[kq1 + 1][r1] = bv1.y;
        Bs[kq1 + 2][r1] = bv1.z;
        Bs[kq1 + 3][r1] = bv1.w;
        __syncthreads();
#pragma unroll
        for (int kk = 0; kk < 16; ++kk) {
            const float4 A0 = *(const float4*)&As[kk][mf];
            const float4 A1 = *(const float4*)&As[kk][mf + 64];
            const float4 B0 = *(const float4*)&Bs[kk][nf];
            const float4 B1 = *(const float4*)&Bs[kk][nf + 64];
            const float a[8] = {A0.x, A0.y, A0.z, A0.w, A1.x, A1.y, A1.z, A1.w};
            const float b[8] = {B0.x, B0.y, B0.z, B0.w, B1.x, B1.y, B1.z, B1.w};
#pragma unroll
            for (int i = 0; i < 8; ++i)
#pragma unroll
                for (int j = 0; j < 8; ++j)
                    acc[i][j] = fmaf(a[i], b[j], acc[i][j]);
        }
        __syncthreads();
    }

#pragma unroll
    for (int i = 0; i < 8; ++i) {
        const int row = m0 + mf + (i & 3) + (i >> 2) * 64;
        const float4 v0 = make_float4(acc[i][0], acc[i][1], acc[i][2], acc[i][3]);
        const float4 v1 = make_float4(acc[i][4], acc[i][5], acc[i][6], acc[i][7]);
        *(float4*)(z + (size_t)row * HIDDEN + n0 + nf)      = v0;
        *(float4*)(z + (size_t)row * HIDDEN + n0 + nf + 64) = v1;
    }
}

__global__ __launch_bounds__(256, 2)
void topk_decode_fb(float* __restrict__ z,
                    const float* __restrict__ dA, const float* __restrict__ dB,
                    const float* __restrict__ po0, const float* __restrict__ po1,
                    float* __restrict__ rec0, float* __restrict__ rec1)
{
    __shared__ float    rowv[HIDDEN];
    __shared__ unsigned hist[4][257];
    __shared__ unsigned scanbuf[256];
    __shared__ float    selv[TOPK];
    __shared__ int      seli[TOPK];
    __shared__ unsigned sh_byte, sh_gt;

    const int tid = threadIdx.x;
    const size_t rowid = blockIdx.x;
    float* __restrict__ zrow = z + rowid * HIDDEN;

#pragma unroll
    for (int s = 0; s < 8; ++s) {
        const int i4 = s * 256 + tid;
        *(float4*)&rowv[i4 * 4] = *(const float4*)&zrow[i4 * 4];
    }
    __syncthreads();

    unsigned prefix = 0, prefmask = 0, need = TOPK;
#pragma unroll
    for (int p = 3; p >= 0; --p) {
        for (int i = tid; i < 4 * 257; i += 256) (&hist[0][0])[i] = 0;
        __syncthreads();
        const int sh = p * 8;
        for (int s = 0; s < 32; ++s) {
            const int i = s * 256 + tid;
            const unsigned k = fkey32(rowv[i]);
            if ((k & prefmask) == prefix)
                atomicAdd(&hist[tid & 3][(k >> sh) & 255], 1);
        }
        __syncthreads();
        const unsigned tot = hist[0][tid] + hist[1][tid] + hist[2][tid] + hist[3][tid];
        hist[0][tid] = tot;
        __syncthreads();
        if (tid == 0) {
            unsigned cum = 0;
            int b = 255;
            for (;; --b) {
                const unsigned c = hist[0][b];
                if (cum + c >= need || b == 0) { sh_byte = (unsigned)b; sh_gt = cum; break; }
                cum += c;
            }
        }
        __syncthreads();
        prefix  |= sh_byte << sh;
        prefmask |= 0xFFu << sh;
        need -= sh_gt;
        __syncthreads();
    }
    const unsigned cut = prefix;
    const unsigned needEq = need;

    unsigned gtmask = 0, eqmask = 0;
#pragma unroll
    for (int j = 0; j < 32; ++j) {
        const int jr = (j + tid) & 31;
        const int i = tid * 32 + jr;
        const unsigned k = fkey32(rowv[i]);
        if (k > cut)       gtmask |= 1u << jr;
        else if (k == cut) eqmask |= 1u << jr;
    }

    scanbuf[tid] = __popc(eqmask);
    __syncthreads();
    for (int off = 1; off < 256; off <<= 1) {
        const unsigned v = scanbuf[tid];
        const unsigned add = (tid >= off) ? scanbuf[tid - off] : 0u;
        __syncthreads();
        scanbuf[tid] = v + add;
        __syncthreads();
    }
    const unsigned eqexc = scanbuf[tid] - __popc(eqmask);
    __syncthreads();

    unsigned selmask = gtmask;
    {
        unsigned m = eqmask, r = eqexc;
        while (m) {
            const int j = __ffs(m) - 1;
            if (r < needEq) selmask |= 1u << j;
            ++r;
            m &= m - 1;
        }
    }

    scanbuf[tid] = __popc(selmask);
    __syncthreads();
    for (int off = 1; off < 256; off <<= 1) {
        const unsigned v = scanbuf[tid];
        const unsigned add = (tid >= off) ? scanbuf[tid - off] : 0u;
        __syncthreads();
        scanbuf[tid] = v + add;
        __syncthreads();
    }
    const unsigned selexc = scanbuf[tid] - __popc(selmask);

#pragma unroll
    for (int j = 0; j < 32; ++j) {
        const int jr = (j + tid) & 31;
        const int i = tid * 32 + jr;
        if ((selmask >> jr) & 1u) {
            const int slot = (int)(selexc + __popc(selmask & ((1u << jr) - 1u)));
            selv[slot] = rowv[i];
            seli[slot] = i;
        } else {
            rowv[i] = 0.0f;
        }
    }
    __syncthreads();

#pragma unroll
    for (int s = 0; s < 8; ++s) {
        const int i4 = s * 256 + tid;
        *(float4*)&zrow[i4 * 4] = *(float4*)&rowv[i4 * 4];
    }

    for (int d = tid; d < DIM0; d += 256) {
        float a = po0[d];
#pragma unroll
        for (int j = 0; j < TOPK; ++j)
            a = fmaf(selv[j], dA[(size_t)d * HIDDEN + seli[j]], a);
        rec0[rowid * DIM0 + d] = a;
    }
    for (int d = tid; d < DIM1; d += 256) {
        float a = po1[d];
#pragma unroll
        for (int j = 0; j < TOPK; ++j)
            a = fmaf(selv[j], dB[(size_t)d * HIDDEN + seli[j]], a);
        rec1[rowid * DIM1 + d] = a;
    }
}

// ===========================================================================
extern "C" void kernel_launch(void* const* d_in, const int* in_sizes, int n_in,
                              void* d_out, int out_size, void* d_ws, size_t ws_size,
                              hipStream_t stream)
{
    const float* x0  = (const float*)d_in[0];
    const float* x1  = (const float*)d_in[1];
    const float* pb0 = (const float*)d_in[2];
    const float* pb1 = (const float*)d_in[3];
    const float* ew0 = (const float*)d_in[4];
    const float* ew1 = (const float*)d_in[5];
    const float* dw0 = (const float*)d_in[6];
    const float* dw1 = (const float*)d_in[7];
    const float* po0 = (const float*)d_in[8];
    const float* po1 = (const float*)d_in[9];
    const int*  srcp = (const int*)d_in[10];

    float* z    = (float*)d_out;
    float* rec0 = z + (size_t)BATCH * HIDDEN;
    float* rec1 = rec0 + (size_t)BATCH * DIM0;

    // ws layout: xb[B][768] | wb[H][768] | dTb0[H][512] | dTb1[H][768] (bf16)
    //            | cnt[B*16] (int, line-padded) | clist[B][128] (u32 packed)
    unsigned short* xb   = (unsigned short*)d_ws;
    unsigned short* wb   = xb   + (size_t)BATCH * DIM1;
    unsigned short* dTb0 = wb   + (size_t)HIDDEN * DIM1;
    unsigned short* dTb1 = dTb0 + (size_t)HIDDEN * DIM0;
    int*            cnt  = (int*)(dTb1 + (size_t)HIDDEN * DIM1);
    unsigned*       clist = (unsigned*)(cnt + (size_t)BATCH * CNT_STRIDE);
    const size_t need = ((size_t)BATCH * DIM1 + (size_t)HIDDEN * DIM1 +
                         (size_t)HIDDEN * DIM0 + (size_t)HIDDEN * DIM1) * sizeof(unsigned short)
                        + (size_t)BATCH * CNT_STRIDE * sizeof(int)
                        + (size_t)BATCH * LIST_CAP * sizeof(unsigned);

    if (ws_size >= need) {
        zero_cnt<<<(BATCH * CNT_STRIDE) / 256, 256, 0, stream>>>(cnt);
        prep_all<<<14336, 256, 0, stream>>>(x0, x1, pb0, pb1, ew0, ew1, dw0, dw1,
                                            srcp, xb, wb, dTb0, dTb1);
        gemm_bf16<<<(BATCH / 128) * (HIDDEN / 128), 256, 0, stream>>>(
            xb, wb, srcp, z, cnt, clist);
        topk_rescore_decode<<<BATCH, 256, 0, stream>>>(
            z, x0, x1, pb0, pb1, ew0, ew1, dTb0, dTb1, po0, po1, rec0, rec1,
            srcp, cnt, clist);
    } else {
        encode_gemm<<<dim3(HIDDEN / 128, BATCH / 128), 256, 0, stream>>>(
            x0, x1, pb0, pb1, ew0, ew1, srcp, z);
        topk_decode_fb<<<BATCH, 256, 0, stream>>>(z, dw0, dw1, po0, po1, rec0, rec1);
    }
}

// Round 18
// 636.869 us; speedup vs baseline: 1.1082x; 1.1082x over previous
//
#include <hip/hip_runtime.h>

// UniversalSAE: z = TopK32((x - pre_bias) @ enc_w.T), rec_i = z @ dec_w_i.T + post_bias_i
// R18: exact revert to R15 (measured best: 643us, absmax 7.8e-3).
// GEMM-fused keyed screening (bf16key|~col u32 lists, LDS-aggregated, one
// padded global atomic per block-row) + topk rank-by-approx-key ->
// exact-fp32 rescore of approx-top-40 -> exact top-32 -> scatter + decode.
// Regular score stores (NT variant regressed R17), separate prep launches.

#define BATCH  16384
#define HIDDEN 8192
#define DIM0   512
#define DIM1   768
#define TOPK   32
#define CAND_MAX 256
#define LIST_CAP 128
#define RESCORE_TOP 40
#define STAGE_CAP 32
#define CNT_STRIDE 16     // one 64B cache line per row counter
#define WIN_LO 36
#define WIN_HI 64

// probe seeds for the fallback bisect
#define KLO_G 0xBECDu
#define KHI_G 0xC020u

typedef __attribute__((ext_vector_type(8))) short bf16x8;
typedef __attribute__((ext_vector_type(8))) unsigned short u16x8;
typedef __attribute__((ext_vector_type(4))) float f32x4;

__device__ __forceinline__ unsigned fkey16(unsigned short h) {
    return (h & 0x8000u) ? (unsigned)((~h) & 0xFFFFu) : (unsigned)(h | 0x8000u);
}
__device__ __forceinline__ unsigned short f2b(float f) {  // fp32 -> bf16 RNE
    unsigned u = __float_as_uint(f);
    unsigned r = (u + 0x7FFFu + ((u >> 16) & 1u)) >> 16;
    return (unsigned short)r;
}
__device__ __forceinline__ float b2f(unsigned short h) {
    return __uint_as_float(((unsigned)h) << 16);
}
__device__ __forceinline__ void load_lds16(const void* g, void* l) {
    __builtin_amdgcn_global_load_lds((const __attribute__((address_space(1))) void*)g,
                                     (__attribute__((address_space(3))) void*)l, 16, 0, 0);
}
__device__ __forceinline__ unsigned fkey32(float f) {
    unsigned u = __float_as_uint(f);
    return (u & 0x80000000u) ? ~u : (u | 0x80000000u);
}

// ===========================================================================
__global__ void zero_cnt(int* __restrict__ cnt)
{
    cnt[blockIdx.x * 256 + threadIdx.x] = 0;   // grid covers BATCH*CNT_STRIDE
}

// ===========================================================================
// convert: x-pb and enc_w to bf16
// ===========================================================================
template<int SRC>
__device__ __forceinline__ void convert_impl(
    const float* __restrict__ x, const float* __restrict__ pb,
    const float* __restrict__ w,
    unsigned short* __restrict__ xb, unsigned short* __restrict__ wb)
{
    constexpr int D = SRC ? DIM1 : DIM0;
    const int nx4 = BATCH * D / 4;
    const int nw4 = HIDDEN * D / 4;
    for (int i = blockIdx.x * blockDim.x + threadIdx.x; i < nx4 + nw4;
         i += gridDim.x * blockDim.x) {
        if (i < nx4) {
            float4 v = ((const float4*)x)[i];
            const int k = (i * 4) % D;
            v.x -= pb[k]; v.y -= pb[k + 1]; v.z -= pb[k + 2]; v.w -= pb[k + 3];
            ushort4 o; o.x = f2b(v.x); o.y = f2b(v.y); o.z = f2b(v.z); o.w = f2b(v.w);
            ((ushort4*)xb)[i] = o;
        } else {
            const float4 v = ((const float4*)w)[i - nx4];
            ushort4 o; o.x = f2b(v.x); o.y = f2b(v.y); o.z = f2b(v.z); o.w = f2b(v.w);
            ((ushort4*)wb)[i - nx4] = o;
        }
    }
}

__global__ void convert_xw(const float* __restrict__ x0, const float* __restrict__ x1,
                           const float* __restrict__ pb0, const float* __restrict__ pb1,
                           const float* __restrict__ w0, const float* __restrict__ w1,
                           const int* __restrict__ srcp,
                           unsigned short* __restrict__ xb, unsigned short* __restrict__ wb)
{
    if (*srcp == 0) convert_impl<0>(x0, pb0, w0, xb, wb);
    else            convert_impl<1>(x1, pb1, w1, xb, wb);
}

__global__ void transpose_dec_bf16(const float* __restrict__ dec,
                                   unsigned short* __restrict__ decT, int DD)
{
    __shared__ float t[32][33];
    const int hb = blockIdx.x * 32, db = blockIdx.y * 32;
    const int lx = threadIdx.x, ly = threadIdx.y;
#pragma unroll
    for (int s = 0; s < 32; s += 8)
        t[ly + s][lx] = dec[(size_t)(db + ly + s) * HIDDEN + hb + lx];
    __syncthreads();
#pragma unroll
    for (int s = 0; s < 32; s += 8)
        decT[(size_t)(hb + ly + s) * DD + db + lx] = f2b(t[lx][ly + s]);
}

// ===========================================================================
// GEMM: bf16 scores into first 16KB of each fp32 z row; LDS-aggregated
// keyed screening -> per-row u32 lists; bx>=32 blocks NT-zero back half.
// ===========================================================================
template<int SRC>
__device__ __forceinline__ void gemm_impl(
    const unsigned short* __restrict__ xb, const unsigned short* __restrict__ wb,
    float* __restrict__ z, int* __restrict__ cnt, unsigned* __restrict__ clist,
    unsigned short* As, unsigned short* Bs)
{
    constexpr int D = SRC ? DIM1 : DIM0;
    constexpr unsigned KTH = SRC ? 0xBF86u : 0xBF5Du;  // ~48/8192 quantile

    const int nwg = gridDim.x;
    int id = blockIdx.x;
    id = (id & 7) * (nwg >> 3) + (id >> 3);      // XCD swizzle (nwg % 8 == 0)
    const int bx = id & 63;
    const int by = id >> 6;
    const int m0 = by * 128, n0 = bx * 128;

    const int tid  = threadIdx.x;
    const int lane = tid & 63;
    const int wid  = tid >> 6;
    const int wr   = wid >> 1;
    const int wc   = wid & 1;
    const int l15  = lane & 15;
    const int g    = lane >> 4;

    f32x4 acc[4][4];
#pragma unroll
    for (int i = 0; i < 4; ++i)
#pragma unroll
        for (int j = 0; j < 4; ++j) acc[i][j] = (f32x4){0.f, 0.f, 0.f, 0.f};

    for (int k0 = 0; k0 < D; k0 += 64) {
#pragma unroll
        for (int q = 0; q < 4; ++q) {
            const int c   = wid * 256 + q * 64 + lane;
            const int row = c >> 3, jb = c & 7;
            const int j   = jb ^ (row & 7);      // pre-swizzled source (rule #21)
            load_lds16(xb + (size_t)(m0 + row) * D + k0 + j * 8,
                       As + (size_t)(wid * 256 + q * 64) * 8);
            load_lds16(wb + (size_t)(n0 + row) * D + k0 + j * 8,
                       Bs + (size_t)(wid * 256 + q * 64) * 8);
        }
        __syncthreads();

#pragma unroll
        for (int kk = 0; kk < 2; ++kk) {
            bf16x8 a[4], b[4];
#pragma unroll
            for (int f = 0; f < 4; ++f) {
                const int rA = wr * 64 + f * 16 + l15;
                const int sA = ((kk * 4 + g) ^ (rA & 7)) * 16;
                a[f] = *(const bf16x8*)((const char*)As + rA * 128 + sA);
                const int rB = wc * 64 + f * 16 + l15;
                const int sB = ((kk * 4 + g) ^ (rB & 7)) * 16;
                b[f] = *(const bf16x8*)((const char*)Bs + rB * 128 + sB);
            }
#pragma unroll
            for (int fi = 0; fi < 4; ++fi)
#pragma unroll
                for (int fj = 0; fj < 4; ++fj)
                    acc[fi][fj] = __builtin_amdgcn_mfma_f32_16x16x32_bf16(
                        a[fi], b[fj], acc[fi][fj], 0, 0, 0);
        }
        __syncthreads();
    }
    // K-loop done; As/Bs free for epilogue aliasing (barrier above drained)

    unsigned* staging   = (unsigned*)As;         // 128*32 u32 = 16 KB
    int*      cnt_local = (int*)Bs;              // 128 ints
    int*      base_sh   = (int*)Bs + 128;        // 128 ints

    if (tid < 128) cnt_local[tid] = 0;
    __syncthreads();

    // epilogue: bf16 scores + LDS-local keyed candidate collection
#pragma unroll
    for (int fi = 0; fi < 4; ++fi) {
        const int rl0 = wr * 64 + fi * 16 + g * 4;        // local row base
#pragma unroll
        for (int fj = 0; fj < 4; ++fj) {
            const int col = n0 + wc * 64 + fj * 16 + l15;
#pragma unroll
            for (int r = 0; r < 4; ++r) {
                const unsigned short sb = f2b(acc[fi][fj][r]);
                unsigned short* zs =
                    (unsigned short*)((char*)z + (size_t)(m0 + rl0 + r) * (HIDDEN * 4));
                zs[col] = sb;
                const unsigned k16 = fkey16(sb);
                if (k16 > KTH) {
                    const int ls = atomicAdd(&cnt_local[rl0 + r], 1);
                    if (ls < STAGE_CAP)
                        staging[(rl0 + r) * STAGE_CAP + ls] =
                            (k16 << 16) | (unsigned)(8191 - col);
                }
            }
        }
    }
    __syncthreads();

    // one padded global atomic per (block,row) with n>0
    if (tid < 128) {
        const int n = cnt_local[tid];
        if (n > 0) {
            const int add = (n > STAGE_CAP) ? 1000 : n;   // overflow -> fallback path
            base_sh[tid] = atomicAdd(&cnt[(size_t)(m0 + tid) * CNT_STRIDE], add);
        }
    }
    __syncthreads();

    // flush staged candidates to global list
    if (tid < 128) {
        const int n = min(cnt_local[tid], STAGE_CAP);
        if (n > 0) {
            const int base = base_sh[tid];
            for (int j = 0; j < n; ++j) {
                const int pos = base + j;
                if (pos < LIST_CAP)
                    clist[(size_t)(m0 + tid) * LIST_CAP + pos] =
                        staging[tid * STAGE_CAP + j];
            }
        }
    }

    // back-half zero: fp32 cols [4096 + (bx-32)*128, +128) for rows [m0, m0+128)
    if (bx >= 32) {
        const f32x4 zv = (f32x4){0.f, 0.f, 0.f, 0.f};
        const int c4 = (4096 >> 2) + (bx - 32) * 32 + (tid & 31);
#pragma unroll
        for (int pass = 0; pass < 16; ++pass) {
            const int r = m0 + pass * 8 + (tid >> 5);
            __builtin_nontemporal_store(zv, (f32x4*)(z + (size_t)r * HIDDEN) + c4);
        }
    }
}

__global__ __launch_bounds__(256, 2)
void gemm_bf16(const unsigned short* __restrict__ xb, const unsigned short* __restrict__ wb,
               const int* __restrict__ srcp, float* __restrict__ z,
               int* __restrict__ cnt, unsigned* __restrict__ clist)
{
    __shared__ unsigned short As[128 * 64];
    __shared__ unsigned short Bs[128 * 64];
    if (*srcp == 0) gemm_impl<0>(xb, wb, z, cnt, clist, As, Bs);
    else            gemm_impl<1>(xb, wb, z, cnt, clist, As, Bs);
}

// ===========================================================================
// topk: list path (cnt in [36,128]) or full-screen fallback; both produce
// packed centry[]; rank by approx key -> rescore approx-top-40 exactly ->
// exact top-32 -> scatter + batched decode.
// ===========================================================================
template<int SRC>
__device__ __forceinline__ void topk_impl(
    float* __restrict__ z,
    const float* __restrict__ xsrc, const float* __restrict__ pb,
    const float* __restrict__ ew,
    const unsigned short* __restrict__ dTb0, const unsigned short* __restrict__ dTb1,
    const float* __restrict__ po0, const float* __restrict__ po1,
    float* __restrict__ rec0, float* __restrict__ rec1,
    const int* __restrict__ cnt, const unsigned* __restrict__ clist,
    float* xs, unsigned* centry, int* cidx, float* cval, unsigned char* cflag,
    int* counts, unsigned* pcounts, int* s_cnt, float* selv, int* seli)
{
    constexpr int D = SRC ? DIM1 : DIM0;

    const int tid = threadIdx.x;
    const size_t row = blockIdx.x;
    float* __restrict__ zrow = z + row * HIDDEN;
    const unsigned short* __restrict__ zsrow =
        (const unsigned short*)((const char*)z + row * (HIDDEN * 4));

    // stage exact (x - pb) row first (loads issue earliest)
    if (tid < D / 4) {
        const float4 xv = ((const float4*)(xsrc + row * D))[tid];
        const float4 pv = ((const float4*)pb)[tid];
        ((float4*)xs)[tid] = make_float4(xv.x - pv.x, xv.y - pv.y,
                                         xv.z - pv.z, xv.w - pv.w);
    }
    if (tid == 0) *s_cnt = 0;

    const int cn = cnt[row * CNT_STRIDE];
    const bool uselist = (cn >= WIN_LO && cn <= LIST_CAP);
    const f32x4 zv4 = (f32x4){0.f, 0.f, 0.f, 0.f};
    int cnC;

    if (uselist) {
        // keyed candidate list from GEMM; skip score read + bisect entirely
        if (tid < cn) centry[tid] = clist[row * LIST_CAP + tid];
#pragma unroll
        for (int s = 0; s < 4; ++s)
            __builtin_nontemporal_store(zv4, (f32x4*)&zrow[(size_t)(s * 256 + tid) * 4]);
        __syncthreads();
        cnC = cn;
    } else {
        // fallback: full screen (keys -> probe -> bisect -> collect packed)
        unsigned pkey[16];
#pragma unroll
        for (int s = 0; s < 4; ++s) {
            const u16x8 v = *(const u16x8*)(zsrow + (size_t)(s * 256 + tid) * 8);
#pragma unroll
            for (int p = 0; p < 4; ++p)
                pkey[s * 4 + p] = fkey16(v[2 * p]) | (fkey16(v[2 * p + 1]) << 16);
        }
#pragma unroll
        for (int s = 0; s < 4; ++s)
            __builtin_nontemporal_store(zv4, (f32x4*)&zrow[(size_t)(s * 256 + tid) * 4]);

        {
            int clo = 0, chi = 0;
#pragma unroll
            for (int p = 0; p < 16; ++p) {
                const unsigned klo16 = pkey[p] & 0xFFFFu, khi16 = pkey[p] >> 16;
                clo += (klo16 > KLO_G) ? 1 : 0;  chi += (klo16 > KHI_G) ? 1 : 0;
                clo += (khi16 > KLO_G) ? 1 : 0;  chi += (khi16 > KHI_G) ? 1 : 0;
            }
            unsigned pk = (unsigned)clo | ((unsigned)chi << 16);
#pragma unroll
            for (int off = 32; off; off >>= 1) pk += __shfl_xor(pk, off);
            if ((tid & 63) == 0) pcounts[tid >> 6] = pk;
        }
        __syncthreads();
        const unsigned ptot = pcounts[0] + pcounts[1] + pcounts[2] + pcounts[3];
        const int tot_lo = (int)(ptot & 0xFFFFu), tot_hi = (int)(ptot >> 16);

        unsigned kappa;
        int found = 0;
        if (tot_lo >= WIN_LO && tot_lo <= WIN_HI)      { kappa = KLO_G; found = 1; }
        else if (tot_hi >= WIN_LO && tot_hi <= WIN_HI) { kappa = KHI_G; found = 1; }
        if (!found) {
            unsigned lo = 0u, hi = 65535u;
            if (tot_lo > WIN_HI) lo = KLO_G;
            if (tot_lo < WIN_LO) hi = KLO_G;
            if (tot_hi > WIN_HI) lo = KHI_G;
            if (tot_hi < WIN_LO) hi = (hi < KHI_G) ? hi : KHI_G;
            kappa = lo;
            for (int it = 0; it < 18; ++it) {
                const unsigned mid = (lo + hi) >> 1;
                int c = 0;
#pragma unroll
                for (int p = 0; p < 16; ++p) {
                    c += ((pkey[p] & 0xFFFFu) > mid) ? 1 : 0;
                    c += ((pkey[p] >> 16)     > mid) ? 1 : 0;
                }
#pragma unroll
                for (int off = 32; off; off >>= 1) c += __shfl_xor(c, off);
                if ((tid & 63) == 0) counts[(it & 1) * 4 + (tid >> 6)] = c;
                __syncthreads();
                const int* cb = counts + (it & 1) * 4;
                const int tot = cb[0] + cb[1] + cb[2] + cb[3];
                if (tot >= WIN_LO && tot <= WIN_HI) { kappa = mid; break; }
                if (tot > WIN_HI) lo = mid; else hi = mid;
                kappa = lo;
                if (hi - lo <= 1u) break;
            }
        }

#pragma unroll
        for (int p = 0; p < 16; ++p) {
#pragma unroll
            for (int h = 0; h < 2; ++h) {
                const unsigned k16 = h ? (pkey[p] >> 16) : (pkey[p] & 0xFFFFu);
                if (k16 > kappa) {
                    const int j = 2 * p + h;
                    const int slot = atomicAdd(s_cnt, 1);
                    if (slot < CAND_MAX) {
                        const int idx = ((j >> 3) * 256 + tid) * 8 + (j & 7);
                        centry[slot] = (k16 << 16) | (unsigned)(8191 - idx);
                    }
                }
            }
        }
        __syncthreads();
        cnC = min(*s_cnt, CAND_MAX);
    }

    // rank by approx key (desc; ties -> lower col wins), keep approx-top-40.
    // Entries are distinct -> unique ranks -> no write conflicts.
    const int C = min(cnC, RESCORE_TOP);
    if (tid < cnC) {
        const unsigned e = centry[tid];
        int rank = 0;
        for (int j = 0; j < cnC; ++j) rank += (centry[j] > e) ? 1 : 0;
        if (rank < RESCORE_TOP) cidx[rank] = 8191 - (int)(e & 0xFFFFu);
    }
    __syncthreads();

    // exact fp32 rescore: 16-lane groups; whole candidate row in one burst
    {
        constexpr int NB = D / 64;                // float4s per lane (8 or 12)
        const int grp = tid >> 4, j16 = tid & 15; // 16 groups of 16 lanes
        for (int c = grp; c < C; c += 16) {
            const float* __restrict__ wrow = ew + (size_t)cidx[c] * D;
            float4 wv[NB];
#pragma unroll
            for (int u = 0; u < NB; ++u)
                wv[u] = *(const float4*)&wrow[(u * 16 + j16) * 4];
            float4 a4 = make_float4(0.f, 0.f, 0.f, 0.f);
#pragma unroll
            for (int u = 0; u < NB; ++u) {
                const float4 x4 = *(const float4*)&xs[(u * 16 + j16) * 4];
                a4.x = fmaf(x4.x, wv[u].x, a4.x);
                a4.y = fmaf(x4.y, wv[u].y, a4.y);
                a4.z = fmaf(x4.z, wv[u].z, a4.z);
                a4.w = fmaf(x4.w, wv[u].w, a4.w);
            }
            float a = (a4.x + a4.y) + (a4.z + a4.w);
            a += __shfl_xor(a, 1);
            a += __shfl_xor(a, 2);
            a += __shfl_xor(a, 4);
            a += __shfl_xor(a, 8);
            if (j16 == 0) cval[c] = a;
        }
    }
    __syncthreads();

    // exact top-32 among C candidates (val desc, idx asc) — order-independent
    if (tid < C) {
        const float v = cval[tid];
        const int  ix = cidx[tid];
        int rank = 0;
        for (int j = 0; j < C; ++j) {
            const float vj = cval[j];
            rank += (vj > v || (vj == v && cidx[j] < ix)) ? 1 : 0;
        }
        cflag[tid] = (rank < TOPK) ? 1 : 0;
    }
    __syncthreads();
    if (tid < C && cflag[tid]) {
        const int ix = cidx[tid];
        int sr = 0;
        for (int j = 0; j < C; ++j) sr += (cflag[j] && cidx[j] < ix) ? 1 : 0;
        selv[sr] = cval[tid];
        seli[sr] = ix;
    }
    __syncthreads();

    // scatter 32 exact values (front zero above, back half by GEMM)
    if (tid < TOPK) zrow[seli[tid]] = selv[tid];

    // batched sparse decode: thread -> 4 consecutive outputs; 16 rows in flight
#pragma unroll
    for (int pass = 0; pass < 2; ++pass) {
        const int slot = pass * 256 + tid;
        if (slot < (DIM0 + DIM1) / 4) {
            const bool is0 = slot < DIM0 / 4;
            const int d0 = is0 ? slot * 4 : (slot - DIM0 / 4) * 4;
            const int DD = is0 ? DIM0 : DIM1;
            const unsigned short* __restrict__ dT = is0 ? dTb0 : dTb1;
            const float* __restrict__ po = is0 ? po0 : po1;
            f32x4 a;
            {
                const float4 p4 = *(const float4*)&po[d0];
                a = (f32x4){p4.x, p4.y, p4.z, p4.w};
            }
#pragma unroll
            for (int b = 0; b < TOPK / 16; ++b) {
                ushort4 wv[16];
#pragma unroll
                for (int u = 0; u < 16; ++u)
                    wv[u] = *(const ushort4*)&dT[(size_t)seli[b * 16 + u] * DD + d0];
#pragma unroll
                for (int u = 0; u < 16; ++u) {
                    const float sv = selv[b * 16 + u];
                    a.x = fmaf(sv, b2f(wv[u].x), a.x);
                    a.y = fmaf(sv, b2f(wv[u].y), a.y);
                    a.z = fmaf(sv, b2f(wv[u].z), a.z);
                    a.w = fmaf(sv, b2f(wv[u].w), a.w);
                }
            }
            float* __restrict__ out = is0 ? (rec0 + row * DIM0 + d0)
                                          : (rec1 + row * DIM1 + d0);
            __builtin_nontemporal_store(a, (f32x4*)out);
        }
    }
}

__global__ __launch_bounds__(256, 4)
void topk_rescore_decode(float* __restrict__ z,
                         const float* __restrict__ x0, const float* __restrict__ x1,
                         const float* __restrict__ pb0, const float* __restrict__ pb1,
                         const float* __restrict__ ew0, const float* __restrict__ ew1,
                         const unsigned short* __restrict__ dTb0,
                         const unsigned short* __restrict__ dTb1,
                         const float* __restrict__ po0, const float* __restrict__ po1,
                         float* __restrict__ rec0, float* __restrict__ rec1,
                         const int* __restrict__ srcp,
                         const int* __restrict__ cnt, const unsigned* __restrict__ clist)
{
    __shared__ float         xs[DIM1];
    __shared__ unsigned      centry[CAND_MAX];
    __shared__ int           cidx[RESCORE_TOP];
    __shared__ float         cval[RESCORE_TOP];
    __shared__ unsigned char cflag[RESCORE_TOP];
    __shared__ int           counts[2 * 4];
    __shared__ unsigned      pcounts[4];
    __shared__ int           s_cnt;
    __shared__ float         selv[TOPK];
    __shared__ int           seli[TOPK];

    if (*srcp == 0)
        topk_impl<0>(z, x0, pb0, ew0, dTb0, dTb1, po0, po1, rec0, rec1, cnt, clist,
                     xs, centry, cidx, cval, cflag, counts, pcounts, &s_cnt, selv, seli);
    else
        topk_impl<1>(z, x1, pb1, ew1, dTb0, dTb1, po0, po1, rec0, rec1, cnt, clist,
                     xs, centry, cidx, cval, cflag, counts, pcounts, &s_cnt, selv, seli);
}

// ===========================================================================
// FALLBACK PATH (round-1, known-pass) — used only if ws is too small
// ===========================================================================

__global__ __launch_bounds__(256, 2)
void encode_gemm(const float* __restrict__ x0, const float* __restrict__ x1,
                 const float* __restrict__ pb0, const float* __restrict__ pb1,
                 const float* __restrict__ w0, const float* __restrict__ w1,
                 const int* __restrict__ srcp, float* __restrict__ z)
{
    const int src = *srcp;
    const float* __restrict__ x  = (src == 0) ? x0 : x1;
    const float* __restrict__ pb = (src == 0) ? pb0 : pb1;
    const float* __restrict__ w  = (src == 0) ? w0 : w1;
    const int D = (src == 0) ? DIM0 : DIM1;

    __shared__ float As[16][132];
    __shared__ float Bs[16][132];

    const int tid = threadIdx.x;
    const int m0 = blockIdx.y * 128;
    const int n0 = blockIdx.x * 128;

    const int cA0 = tid,          cA1 = tid + 256;
    const int r0  = cA0 >> 2,     kq0 = (cA0 & 3) * 4;
    const int r1  = cA1 >> 2,     kq1 = (cA1 & 3) * 4;

    const int mf = (tid & 15) * 4;
    const int nf = (tid >> 4) * 4;

    float acc[8][8];
#pragma unroll
    for (int i = 0; i < 8; ++i)
#pragma unroll
        for (int j = 0; j < 8; ++j) acc[i][j] = 0.0f;

    for (int k0 = 0; k0 < D; k0 += 16) {
        const float4 av0 = *(const float4*)(x + (size_t)(m0 + r0) * D + k0 + kq0);
        const float4 av1 = *(const float4*)(x + (size_t)(m0 + r1) * D + k0 + kq1);
        const float4 pv0 = *(const float4*)(pb + k0 + kq0);
        const float4 pv1 = *(const float4*)(pb + k0 + kq1);
        const float4 bv0 = *(const float4*)(w + (size_t)(n0 + r0) * D + k0 + kq0);
        const float4 bv1 = *(const float4*)(w + (size_t)(n0 + r1) * D + k0 + kq1);
        As[kq0 + 0][r0] = av0.x - pv0.x;
        As[kq0 + 1][r0] = av0.y - pv0.y;
        As[kq0 + 2][r0] = av0.z - pv0.z;
        As[kq0 + 3][r0] = av0.w - pv0.w;
        As[kq1 + 0][r1] = av1.x - pv1.x;
        As[kq1 + 1][r1] = av1.y - pv1.y;
        As[kq1 + 2][r1] = av1.z - pv1.z;
        As[kq1 + 3][r1] = av1.w - pv1.w;
        Bs[kq0 + 0][r0] = bv0.x;
        Bs[kq0 + 1][r0] = bv0.y;
        Bs[kq0 + 2][r0] = bv0.z;
        Bs[kq0 + 3][r0] = bv0.w;
        Bs[kq1 + 0][r1] = bv1.x;
        Bs[kq1 + 1][r1] = bv1.y;
        Bs[kq1 + 2][r1] = bv1.z;
        Bs[kq1 + 3][r1] = bv1.w;
        __syncthreads();
#pragma unroll
        for (int kk = 0; kk < 16; ++kk) {
            const float4 A0 = *(const float4*)&As[kk][mf];
            const float4 A1 = *(const float4*)&As[kk][mf + 64];
            const float4 B0 = *(const float4*)&Bs[kk][nf];
            const float4 B1 = *(const float4*)&Bs[kk][nf + 64];
            const float a[8] = {A0.x, A0.y, A0.z, A0.w, A1.x, A1.y, A1.z, A1.w};
            const float b[8] = {B0.x, B0.y, B0.z, B0.w, B1.x, B1.y, B1.z, B1.w};
#pragma unroll
            for (int i = 0; i < 8; ++i)
#pragma unroll
                for (int j = 0; j < 8; ++j)
                    acc[i][j] = fmaf(a[i], b[j], acc[i][j]);
        }
        __syncthreads();
    }

#pragma unroll
    for (int i = 0; i < 8; ++i) {
        const int row = m0 + mf + (i & 3) + (i >> 2) * 64;
        const float4 v0 = make_float4(acc[i][0], acc[i][1], acc[i][2], acc[i][3]);
        const float4 v1 = make_float4(acc[i][4], acc[i][5], acc[i][6], acc[i][7]);
        *(float4*)(z + (size_t)row * HIDDEN + n0 + nf)      = v0;
        *(float4*)(z + (size_t)row * HIDDEN + n0 + nf + 64) = v1;
    }
}

__global__ __launch_bounds__(256, 2)
void topk_decode_fb(float* __restrict__ z,
                    const float* __restrict__ dA, const float* __restrict__ dB,
                    const float* __restrict__ po0, const float* __restrict__ po1,
                    float* __restrict__ rec0, float* __restrict__ rec1)
{
    __shared__ float    rowv[HIDDEN];
    __shared__ unsigned hist[4][257];
    __shared__ unsigned scanbuf[256];
    __shared__ float    selv[TOPK];
    __shared__ int      seli[TOPK];
    __shared__ unsigned sh_byte, sh_gt;

    const int tid = threadIdx.x;
    const size_t rowid = blockIdx.x;
    float* __restrict__ zrow = z + rowid * HIDDEN;

#pragma unroll
    for (int s = 0; s < 8; ++s) {
        const int i4 = s * 256 + tid;
        *(float4*)&rowv[i4 * 4] = *(const float4*)&zrow[i4 * 4];
    }
    __syncthreads();

    unsigned prefix = 0, prefmask = 0, need = TOPK;
#pragma unroll
    for (int p = 3; p >= 0; --p) {
        for (int i = tid; i < 4 * 257; i += 256) (&hist[0][0])[i] = 0;
        __syncthreads();
        const int sh = p * 8;
        for (int s = 0; s < 32; ++s) {
            const int i = s * 256 + tid;
            const unsigned k = fkey32(rowv[i]);
            if ((k & prefmask) == prefix)
                atomicAdd(&hist[tid & 3][(k >> sh) & 255], 1);
        }
        __syncthreads();
        const unsigned tot = hist[0][tid] + hist[1][tid] + hist[2][tid] + hist[3][tid];
        hist[0][tid] = tot;
        __syncthreads();
        if (tid == 0) {
            unsigned cum = 0;
            int b = 255;
            for (;; --b) {
                const unsigned c = hist[0][b];
                if (cum + c >= need || b == 0) { sh_byte = (unsigned)b; sh_gt = cum; break; }
                cum += c;
            }
        }
        __syncthreads();
        prefix  |= sh_byte << sh;
        prefmask |= 0xFFu << sh;
        need -= sh_gt;
        __syncthreads();
    }
    const unsigned cut = prefix;
    const unsigned needEq = need;

    unsigned gtmask = 0, eqmask = 0;
#pragma unroll
    for (int j = 0; j < 32; ++j) {
        const int jr = (j + tid) & 31;
        const int i = tid * 32 + jr;
        const unsigned k = fkey32(rowv[i]);
        if (k > cut)       gtmask |= 1u << jr;
        else if (k == cut) eqmask |= 1u << jr;
    }

    scanbuf[tid] = __popc(eqmask);
    __syncthreads();
    for (int off = 1; off < 256; off <<= 1) {
        const unsigned v = scanbuf[tid];
        const unsigned add = (tid >= off) ? scanbuf[tid - off] : 0u;
        __syncthreads();
        scanbuf[tid] = v + add;
        __syncthreads();
    }
    const unsigned eqexc = scanbuf[tid] - __popc(eqmask);
    __syncthreads();

    unsigned selmask = gtmask;
    {
        unsigned m = eqmask, r = eqexc;
        while (m) {
            const int j = __ffs(m) - 1;
            if (r < needEq) selmask |= 1u << j;
            ++r;
            m &= m - 1;
        }
    }

    scanbuf[tid] = __popc(selmask);
    __syncthreads();
    for (int off = 1; off < 256; off <<= 1) {
        const unsigned v = scanbuf[tid];
        const unsigned add = (tid >= off) ? scanbuf[tid - off] : 0u;
        __syncthreads();
        scanbuf[tid] = v + add;
        __syncthreads();
    }
    const unsigned selexc = scanbuf[tid] - __popc(selmask);

#pragma unroll
    for (int j = 0; j < 32; ++j) {
        const int jr = (j + tid) & 31;
        const int i = tid * 32 + jr;
        if ((selmask >> jr) & 1u) {
            const int slot = (int)(selexc + __popc(selmask & ((1u << jr) - 1u)));
            selv[slot] = rowv[i];
            seli[slot] = i;
        } else {
            rowv[i] = 0.0f;
        }
    }
    __syncthreads();

#pragma unroll
    for (int s = 0; s < 8; ++s) {
        const int i4 = s * 256 + tid;
        *(float4*)&zrow[i4 * 4] = *(float4*)&rowv[i4 * 4];
    }

    for (int d = tid; d < DIM0; d += 256) {
        float a = po0[d];
#pragma unroll
        for (int j = 0; j < TOPK; ++j)
            a = fmaf(selv[j], dA[(size_t)d * HIDDEN + seli[j]], a);
        rec0[rowid * DIM0 + d] = a;
    }
    for (int d = tid; d < DIM1; d += 256) {
        float a = po1[d];
#pragma unroll
        for (int j = 0; j < TOPK; ++j)
            a = fmaf(selv[j], dB[(size_t)d * HIDDEN + seli[j]], a);
        rec1[rowid * DIM1 + d] = a;
    }
}

// ===========================================================================
extern "C" void kernel_launch(void* const* d_in, const int* in_sizes, int n_in,
                              void* d_out, int out_size, void* d_ws, size_t ws_size,
                              hipStream_t stream)
{
    const float* x0  = (const float*)d_in[0];
    const float* x1  = (const float*)d_in[1];
    const float* pb0 = (const float*)d_in[2];
    const float* pb1 = (const float*)d_in[3];
    const float* ew0 = (const float*)d_in[4];
    const float* ew1 = (const float*)d_in[5];
    const float* dw0 = (const float*)d_in[6];
    const float* dw1 = (const float*)d_in[7];
    const float* po0 = (const float*)d_in[8];
    const float* po1 = (const float*)d_in[9];
    const int*  srcp = (const int*)d_in[10];

    float* z    = (float*)d_out;
    float* rec0 = z + (size_t)BATCH * HIDDEN;
    float* rec1 = rec0 + (size_t)BATCH * DIM0;

    // ws layout: xb[B][768] | wb[H][768] | dTb0[H][512] | dTb1[H][768] (bf16)
    //            | cnt[B*16] (int, line-padded) | clist[B][128] (u32 packed)
    unsigned short* xb   = (unsigned short*)d_ws;
    unsigned short* wb   = xb   + (size_t)BATCH * DIM1;
    unsigned short* dTb0 = wb   + (size_t)HIDDEN * DIM1;
    unsigned short* dTb1 = dTb0 + (size_t)HIDDEN * DIM0;
    int*            cnt  = (int*)(dTb1 + (size_t)HIDDEN * DIM1);
    unsigned*       clist = (unsigned*)(cnt + (size_t)BATCH * CNT_STRIDE);
    const size_t need = ((size_t)BATCH * DIM1 + (size_t)HIDDEN * DIM1 +
                         (size_t)HIDDEN * DIM0 + (size_t)HIDDEN * DIM1) * sizeof(unsigned short)
                        + (size_t)BATCH * CNT_STRIDE * sizeof(int)
                        + (size_t)BATCH * LIST_CAP * sizeof(unsigned);

    if (ws_size >= need) {
        zero_cnt<<<(BATCH * CNT_STRIDE) / 256, 256, 0, stream>>>(cnt);
        convert_xw<<<4096, 256, 0, stream>>>(x0, x1, pb0, pb1, ew0, ew1, srcp, xb, wb);
        dim3 tb(32, 8);
        transpose_dec_bf16<<<dim3(HIDDEN / 32, DIM0 / 32), tb, 0, stream>>>(dw0, dTb0, DIM0);
        transpose_dec_bf16<<<dim3(HIDDEN / 32, DIM1 / 32), tb, 0, stream>>>(dw1, dTb1, DIM1);
        gemm_bf16<<<(BATCH / 128) * (HIDDEN / 128), 256, 0, stream>>>(
            xb, wb, srcp, z, cnt, clist);
        topk_rescore_decode<<<BATCH, 256, 0, stream>>>(
            z, x0, x1, pb0, pb1, ew0, ew1, dTb0, dTb1, po0, po1, rec0, rec1,
            srcp, cnt, clist);
    } else {
        encode_gemm<<<dim3(HIDDEN / 128, BATCH / 128), 256, 0, stream>>>(
            x0, x1, pb0, pb1, ew0, ew1, srcp, z);
        topk_decode_fb<<<BATCH, 256, 0, stream>>>(z, dw0, dw1, po0, po1, rec0, rec1);
    }
}